// Round 7
// baseline (371.961 us; speedup 1.0000x reference)
//
#include <hip/hip_runtime.h>

// Caps layer: B=256 batches, S=512 input caps, D=256 in-dim, NC=16, DC=32, O=512.
// One block per batch; grid 256 = 1 block/CU (structural). 512 thr, 8 waves.
// R7 change: fuse b-pass and y-pass per 32-s pair; kill the LDS x-transpose.
// R6 paid for MFMA-y with: a 2nd HBM x-pass (FETCH 235->330 MB), 8-way
// transpose-write bank conflicts (295K->1.74M), 16 barriers/iter, and ~4K
// VALU insts/lane of staging conversion. Fix: the y B-frag
// B[k=s][col=d] = x[s0p + l4*8+j][d0 + l15] is readable DIRECTLY from global
// in fragment layout (4x64B segments/instr). Run y-MFMA right after the
// b-tile MFMA that just read the same 32 rows -> L1/L2-hot, one x-pass/iter.
// Per-wave partial y (floatx4 acc[16], K=64 local) reduced via LDS atomicAdd
// (ytmp rows padded to 264 -> 2-way banks). c handoff is wave-local (per-wave
// cds region, 80 B rows -> 2-way banks). Barriers/iter: ~19 -> 3.
// Numerics identical to R6 (split-bf16 c and x, 3-term MFMA, drop cl*xl).
// Factorized routing (u_hat never materialized):
//   y[n][D]   = sum_s c[n][s] x[s][D]            (MFMA, split-bf16, f32 acc)
//   outputs   = squash_d( y[n] . W[:, n*32+d] )
//   z[n][D]   = sum_d W[D][n*32+d] outputs[n][d]
//   b[n][s]   = sum_D x[s][D] z[n][D]            (MFMA 16x16x32 bf16, f32 acc)

#define S_ 512
#define D_ 256
#define O_ 512

typedef __attribute__((ext_vector_type(8))) short short8;
typedef __attribute__((ext_vector_type(4))) float floatx4;

__device__ __forceinline__ unsigned short f2b(float f) {
  union { float ff; unsigned int i; } v; v.ff = f;
  unsigned int u = v.i;
  return (unsigned short)((u + 0x7FFFu + ((u >> 16) & 1u)) >> 16);
}
__device__ __forceinline__ float b2f(unsigned short h) {
  union { unsigned int i; float ff; } v; v.i = ((unsigned int)h) << 16;
  return v.ff;
}

__global__ __launch_bounds__(512, 2) void caps_kernel(
    const float* __restrict__ x, const float* __restrict__ W,
    float* __restrict__ out)
{
  // LDS (47872 B):
  //   ytmp f32 16x264 = 16896 B: y[n][D], rows pad 264 (2-way atomics);
  //                              iters 1,2 accumulate via ds atomicAdd
  //   zb   u16 16x264 =  8448 B: z bf16 (528 B rows, MFMA A-frag source)
  //   outp f32 512    =  2048 B
  //   cds  u16 [2][8][16][40] = 20480 B: per-wave c split-bf16 pair-tile
  //        (rows 80 B -> 2-way A-frag reads); iter-0 rowsum alias (8 KB)
  __shared__ __align__(16) float ytmp[16 * 264];
  __shared__ __align__(16) unsigned short zb[16 * 264];
  __shared__ __align__(16) float outp[O_];
  __shared__ __align__(16) unsigned short cds[2][8][16][40];

  const int tid  = threadIdx.x;
  const int wave = tid >> 6;
  const int lane = tid & 63;
  const int l15  = lane & 15;
  const int l4   = lane >> 4;
  const float* xb = x + (size_t)blockIdx.x * (S_ * D_);

  for (int it = 0; it < 3; ++it) {
    if (it == 0) {
      // ---- iter 0: b=0 -> c=1/16 uniform -> y[n][:] = (1/16)*rowsum(x) ----
      float a0 = 0.f, a1 = 0.f, a2 = 0.f, a3 = 0.f;
      #pragma unroll 4
      for (int r = 0; r < 64; ++r) {
        const int s = (wave << 6) + r;
        const float4 xv = *(const float4*)(xb + s * D_ + (lane << 2));
        a0 += xv.x; a1 += xv.y; a2 += xv.z; a3 += xv.w;
      }
      float* rs = (float*)cds;   // alias: 8 waves x 256 f32 strips (8 KB)
      *(float4*)(rs + (wave << 8) + (lane << 2)) = make_float4(a0, a1, a2, a3);
      __syncthreads();
      if (tid < 256) {
        float v = 0.f;
        #pragma unroll
        for (int w = 0; w < 8; ++w) v += rs[(w << 8) + tid];
        v *= 0.0625f;
        #pragma unroll
        for (int n = 0; n < 16; ++n) ytmp[n * 264 + tid] = v;
      }
      __syncthreads();
    } else {
      // ---- FUSED pass: per 32-s pair: 2 b-tiles+softmax -> c -> y-MFMA ----
      floatx4 acc[16];
      #pragma unroll
      for (int dt = 0; dt < 16; ++dt) acc[dt] = (floatx4){0.f, 0.f, 0.f, 0.f};

      #pragma unroll 1
      for (int p = 0; p < 2; ++p) {
        const int s0p = (wave << 6) + (p << 5);
        // -- two b-tiles (16 s each) + softmax -> c split-bf16 to wave cds --
        #pragma unroll 1
        for (int h = 0; h < 2; ++h) {
          const int s0 = s0p + (h << 4);
          floatx4 C = {0.f, 0.f, 0.f, 0.f};
          #pragma unroll
          for (int k = 0; k < 8; ++k) {
            // A-frag: z[m=l15][k*32 + l4*8 + j] from LDS
            const short8 A = *(const short8*)(zb + l15 * 264 + (k << 5) + (l4 << 3));
            // B-frag: x[s0+l15][k*32 + l4*8 + j] fp32 global -> bf16
            const float* xp = xb + (s0 + l15) * D_ + (k << 5) + (l4 << 3);
            const float4 xv0 = *(const float4*)xp;
            const float4 xv1 = *(const float4*)(xp + 4);
            short8 Bf;
            Bf[0] = (short)f2b(xv0.x); Bf[1] = (short)f2b(xv0.y);
            Bf[2] = (short)f2b(xv0.z); Bf[3] = (short)f2b(xv0.w);
            Bf[4] = (short)f2b(xv1.x); Bf[5] = (short)f2b(xv1.y);
            Bf[6] = (short)f2b(xv1.z); Bf[7] = (short)f2b(xv1.w);
            C = __builtin_amdgcn_mfma_f32_16x16x32_bf16(A, Bf, C, 0, 0, 0);
          }
          // C/D layout: col = l15 (s), row = l4*4 + rg (n).
          float m = fmaxf(fmaxf(C[0], C[1]), fmaxf(C[2], C[3]));
          m = fmaxf(m, __shfl_xor(m, 16, 64));
          m = fmaxf(m, __shfl_xor(m, 32, 64));
          const float e0 = __expf(C[0] - m), e1 = __expf(C[1] - m);
          const float e2 = __expf(C[2] - m), e3 = __expf(C[3] - m);
          float sm = e0 + e1 + e2 + e3;
          sm += __shfl_xor(sm, 16, 64);
          sm += __shfl_xor(sm, 32, 64);
          const float inv = 1.f / sm;
          const int nb = l4 << 2;
          const int sc = (h << 4) + l15;
          float vs[4] = {e0 * inv, e1 * inv, e2 * inv, e3 * inv};
          #pragma unroll
          for (int rg = 0; rg < 4; ++rg) {
            const float v = vs[rg];
            const unsigned short ch = f2b(v);
            const unsigned short cl = f2b(v - b2f(ch));
            cds[0][wave][nb + rg][sc] = ch;
            cds[1][wave][nb + rg][sc] = cl;
          }
        }
        // wave-local RAW on cds: drain LDS writes (no block barrier needed)
        asm volatile("s_waitcnt lgkmcnt(0)" ::: "memory");
        // A-frags for the pair: c[n=l15][k=l4*8+j], k over the pair's 32 s
        const short8 Ah = *(const short8*)&cds[0][wave][l15][l4 << 3];
        const short8 Al = *(const short8*)&cds[1][wave][l15][l4 << 3];
        // -- y-MFMA: 16 d-tiles; B-frags direct from global (L1/L2-hot) --
        #pragma unroll
        for (int dt = 0; dt < 16; ++dt) {
          const int d0 = dt << 4;
          short8 Bh, Bl;
          #pragma unroll
          for (int j = 0; j < 8; ++j) {
            const float v = xb[(size_t)(s0p + (l4 << 3) + j) * D_ + d0 + l15];
            const unsigned short hh = f2b(v);
            Bh[j] = (short)hh; Bl[j] = (short)f2b(v - b2f(hh));
          }
          acc[dt] = __builtin_amdgcn_mfma_f32_16x16x32_bf16(Ah, Bh, acc[dt], 0, 0, 0);
          acc[dt] = __builtin_amdgcn_mfma_f32_16x16x32_bf16(Al, Bh, acc[dt], 0, 0, 0);
          acc[dt] = __builtin_amdgcn_mfma_f32_16x16x32_bf16(Ah, Bl, acc[dt], 0, 0, 0);
        }
      }
      // reduce partial y across waves: LDS atomicAdd (2-way banks, no rounds)
      // C/D layout: col = l15 (d within tile), row = l4*4 + rg (n)
      #pragma unroll
      for (int dt = 0; dt < 16; ++dt) {
        #pragma unroll
        for (int rg = 0; rg < 4; ++rg)
          atomicAdd(&ytmp[((l4 << 2) + rg) * 264 + (dt << 4) + l15], acc[dt][rg]);
      }
      __syncthreads();
    }

    // ---- outputs[n][d] = sum_D y[n][D] * W[D][n*32+d], then squash over d ----
    {
      const int o = tid;
      const int n = o >> 5;
      float a = 0.f;
      for (int Db = 0; Db < 32; ++Db) {
        const float4 y0 = *(const float4*)(ytmp + n * 264 + (Db << 3));
        const float4 y1 = *(const float4*)(ytmp + n * 264 + (Db << 3) + 4);
        const float* wp = W + (size_t)(Db << 3) * O_ + o;   // coalesced over o
        a += y0.x * wp[0 * O_]; a += y0.y * wp[1 * O_];
        a += y0.z * wp[2 * O_]; a += y0.w * wp[3 * O_];
        a += y1.x * wp[4 * O_]; a += y1.y * wp[5 * O_];
        a += y1.z * wp[6 * O_]; a += y1.w * wp[7 * O_];
      }
      float ss = a * a;
      #pragma unroll
      for (int off = 1; off < 32; off <<= 1) ss += __shfl_xor(ss, off, 64);
      const float v = a / sqrtf(ss + 1e-7f);
      outp[o] = v;
      if (it == 2) out[(size_t)blockIdx.x * O_ + o] = v;
    }
    __syncthreads();

    if (it < 2) {
      // ---- z[n][D] = sum_d W[D][n*32+d] * outputs[n][d]; wave owns 32 D-rows ----
      {
        const int obase = lane << 3;
        const int n_ln  = lane >> 2;
        float ov[8];
        #pragma unroll
        for (int j = 0; j < 8; ++j) ov[j] = outp[obase + j];
        for (int r = 0; r < 32; ++r) {
          const int Dd = (wave << 5) + r;
          const float4 w0 = *(const float4*)(W + (size_t)Dd * O_ + obase);
          const float4 w1 = *(const float4*)(W + (size_t)Dd * O_ + obase + 4);
          float a = w0.x * ov[0] + w0.y * ov[1] + w0.z * ov[2] + w0.w * ov[3]
                  + w1.x * ov[4] + w1.y * ov[5] + w1.z * ov[6] + w1.w * ov[7];
          a += __shfl_xor(a, 1, 64);
          a += __shfl_xor(a, 2, 64);
          if ((lane & 3) == 0) zb[n_ln * 264 + Dd] = f2b(a);
        }
      }
      // zero ytmp for next iter's atomic accumulation (after squash read it)
      for (int i = tid; i < 16 * 264; i += 512) ytmp[i] = 0.f;
      __syncthreads();
    }
  }
}

extern "C" void kernel_launch(void* const* d_in, const int* in_sizes, int n_in,
                              void* d_out, int out_size, void* d_ws, size_t ws_size,
                              hipStream_t stream) {
  const float* x = (const float*)d_in[0];   // [256, 512, 256] f32
  const float* W = (const float*)d_in[1];   // [256, 512] f32
  float* out = (float*)d_out;               // [256*512] f32
  (void)in_sizes; (void)n_in; (void)out_size; (void)d_ws; (void)ws_size;
  caps_kernel<<<256, 512, 0, stream>>>(x, W, out);
}